// Round 16
// baseline (422.488 us; speedup 1.0000x reference)
//
#include <hip/hip_runtime.h>
#include <hip/hip_bf16.h>

// Problem constants
#define BB   2
#define SS   512
#define TT_  64
#define DD   256
#define HH   8
#define DKK  32
#define FFF  1024
#define NTOK 65536           // B*S*T
#define EPSV 1e-5f
#define SCALE 0.17677669529663687f   // 1/sqrt(32)
#define S2F   0.25503486f            // SCALE * log2(e): folded into Q projection
#define KPS  40              // space_attn K row stride (80B rows, proven)
#define KP   40              // time_attn K stride
#define VH   136             // space Vt row stride (272B)
#define VP6  80              // time_attn Vt row stride

typedef unsigned short u16;
typedef unsigned int   u32;
typedef __attribute__((ext_vector_type(8))) short bf16x8;
typedef __attribute__((ext_vector_type(4))) short bf16x4;
typedef __attribute__((ext_vector_type(4))) float f32x4;

#if __has_builtin(__builtin_amdgcn_exp2f)
#define EXP2(x) __builtin_amdgcn_exp2f(x)
#else
#define EXP2(x) exp2f(x)
#endif

// ---------- helpers ----------
__device__ __forceinline__ float bf2f(u32 u) {
    union { u32 i; float f; } c; c.i = u << 16; return c.f;
}
__device__ __forceinline__ u16 f2bf(float f) {
    __hip_bfloat16 h = __float2bfloat16(f);
    return *reinterpret_cast<u16*>(&h);
}
__device__ __forceinline__ u32 cvtpk2(float lo, float hi) {
    float2 f; f.x = lo; f.y = hi;
    __hip_bfloat162 h2 = __float22bfloat162_rn(f);
    union { __hip_bfloat162 h; u32 u; } c; c.h = h2;
    return c.u;
}
__device__ __forceinline__ void load8v(const float* p, float* v) {
    *(float4*)(v)     = *(const float4*)(p);
    *(float4*)(v + 4) = *(const float4*)(p + 4);
}
__device__ __forceinline__ void load8v(const u16* p, float* v) {
    uint4 raw = *(const uint4*)(p);
    v[0] = bf2f(raw.x & 0xffffu); v[1] = bf2f(raw.x >> 16);
    v[2] = bf2f(raw.y & 0xffffu); v[3] = bf2f(raw.y >> 16);
    v[4] = bf2f(raw.z & 0xffffu); v[5] = bf2f(raw.z >> 16);
    v[6] = bf2f(raw.w & 0xffffu); v[7] = bf2f(raw.w >> 16);
}
__device__ __forceinline__ void load4v(const float* p, float* v) {
    float4 t = *(const float4*)p; v[0] = t.x; v[1] = t.y; v[2] = t.z; v[3] = t.w;
}
__device__ __forceinline__ void load4v(const u16* p, float* v) {
    uint2 raw = *(const uint2*)p;
    v[0] = bf2f(raw.x & 0xffffu); v[1] = bf2f(raw.x >> 16);
    v[2] = bf2f(raw.y & 0xffffu); v[3] = bf2f(raw.y >> 16);
}
__device__ __forceinline__ uint4 pack8bf(const float* v) {
    uint4 r;
    r.x = cvtpk2(v[0], v[1]); r.y = cvtpk2(v[2], v[3]);
    r.z = cvtpk2(v[4], v[5]); r.w = cvtpk2(v[6], v[7]);
    return r;
}
__device__ __forceinline__ uint2 pack4bf(const float* v) {
    uint2 r;
    r.x = cvtpk2(v[0], v[1]); r.y = cvtpk2(v[2], v[3]);
    return r;
}
__device__ __forceinline__ bf16x4 packbf4(const float* v) {
    union { uint2 u; bf16x4 h; } c;
    c.u = pack4bf(v);
    return c.h;
}
__device__ __forceinline__ void store4o(float* p, const float* v) {
    float4 t; t.x = v[0]; t.y = v[1]; t.z = v[2]; t.w = v[3];
    *(float4*)p = t;
}
__device__ __forceinline__ void store4o(u16* p, const float* v) {
    *(uint2*)p = pack4bf(v);
}
__device__ __forceinline__ float rload(const float* p) { return *p; }
__device__ __forceinline__ float rload(const u16* p)  { return bf2f(*p); }
__device__ __forceinline__ void sstore(float* p, float v) { *p = v; }
__device__ __forceinline__ void sstore(u16* p, float v)   { *p = f2bf(v); }
__device__ __forceinline__ void gl16(const u16* gsrc, u16* ldst) {
    __builtin_amdgcn_global_load_lds(
        (const __attribute__((address_space(1))) void*)gsrc,
        (__attribute__((address_space(3))) void*)ldst, 16, 0, 0);
}

#if __has_builtin(__builtin_amdgcn_mfma_f32_16x16x16bf16_1k)
__device__ __forceinline__ f32x4 mfma16(bf16x4 a, bf16x4 b, f32x4 c) {
    return __builtin_amdgcn_mfma_f32_16x16x16bf16_1k(a, b, c, 0, 0, 0);
}
#else
__device__ __forceinline__ f32x4 mfma16(bf16x4 a, bf16x4 b, f32x4 c) {
    asm("v_mfma_f32_16x16x16_bf16 %0, %1, %2, %0" : "+v"(c) : "v"(a), "v"(b));
    return c;
}
#endif

#define BF16_ONE ((short)0x3F80)

// ---------- weight transpose: WT[m][k] = bf16(W[k][m] * scale) ----------
__global__ __launch_bounds__(256)
void transpose_w(const float* __restrict__ W, u16* __restrict__ WT, int K, int M,
                 float scale)
{
    __shared__ float t[32][33];
    const int mb = blockIdx.x * 32;
    const int kb = blockIdx.y * 32;
    const int lx = threadIdx.x & 31;
    const int ly = threadIdx.x >> 5;
    #pragma unroll
    for (int i = ly; i < 32; i += 8) t[i][lx] = W[(size_t)(kb + i) * M + mb + lx];
    __syncthreads();
    #pragma unroll
    for (int i = ly; i < 32; i += 8) WT[(size_t)(mb + i) * K + kb + lx] = f2bf(t[lx][i] * scale);
}

// ---------- batched 256x256 transpose: 4 weights in ONE dispatch (z-indexed) ----------
__global__ __launch_bounds__(256)
void transpose_w4(const float* __restrict__ W0, const float* __restrict__ W1,
                  const float* __restrict__ W2, const float* __restrict__ W3,
                  u16* __restrict__ T0, u16* __restrict__ T1,
                  u16* __restrict__ T2, u16* __restrict__ T3, float s0)
{
    __shared__ float t[32][33];
    const int z = blockIdx.z;
    const float* W = (z == 0) ? W0 : (z == 1) ? W1 : (z == 2) ? W2 : W3;
    u16*       WT = (z == 0) ? T0 : (z == 1) ? T1 : (z == 2) ? T2 : T3;
    const float scale = (z == 0) ? s0 : 1.0f;
    const int mb = blockIdx.x * 32;
    const int kb = blockIdx.y * 32;
    const int lx = threadIdx.x & 31;
    const int ly = threadIdx.x >> 5;
    #pragma unroll
    for (int i = ly; i < 32; i += 8) t[i][lx] = W[(size_t)(kb + i) * DD + mb + lx];
    __syncthreads();
    #pragma unroll
    for (int i = ly; i < 32; i += 8) WT[(size_t)(mb + i) * DD + kb + lx] = f2bf(t[lx][i] * scale);
}

// ---------- pack 3 bias vectors (first one scaled) ----------
__global__ __launch_bounds__(256)
void pack_bias3(const float* __restrict__ a, const float* __restrict__ b,
                const float* __restrict__ c, float* __restrict__ out, float s0)
{
    const int i = threadIdx.x;
    out[i] = a[i] * s0; out[256 + i] = b[i]; out[512 + i] = c[i];
}

// ---------- fuse to-projection into space-QKV (proven r15-r18) ----------
__global__ __launch_bounds__(256)
void fuse_to_sqkv_w(const float* __restrict__ to_w,
                    const float* __restrict__ sq_w, const float* __restrict__ sk_w,
                    const float* __restrict__ sv_w, u16* __restrict__ wt_out)
{
    const int m = blockIdx.x;            // 0..767
    const int k = threadIdx.x;           // 0..255
    const float* Wsq = (m < 256) ? sq_w : (m < 512 ? sk_w : sv_w);
    const int mc = m & 255;
    float acc = 0.f;
    for (int j = 0; j < 256; j++)
        acc += to_w[k * 256 + j] * Wsq[j * 256 + mc];
    if (m < 256) acc *= S2F;
    wt_out[m * 256 + k] = f2bf(acc);
}
__global__ __launch_bounds__(256)
void fuse_to_sqkv_b(const float* __restrict__ to_b,
                    const float* __restrict__ sq_w, const float* __restrict__ sk_w,
                    const float* __restrict__ sv_w,
                    const float* __restrict__ sq_b, const float* __restrict__ sk_b,
                    const float* __restrict__ sv_b, float* __restrict__ b_out)
{
    const int m = blockIdx.x * 256 + threadIdx.x;
    const float* Wsq = (blockIdx.x == 0) ? sq_w : (blockIdx.x == 1 ? sk_w : sv_w);
    const float* bs  = (blockIdx.x == 0) ? sq_b : (blockIdx.x == 1 ? sk_b : sv_b);
    const int mc = m & 255;
    float acc = bs[mc];
    for (int j = 0; j < 256; j++) acc += to_b[j] * Wsq[j * 256 + mc];
    if (blockIdx.x == 0) acc *= S2F;
    b_out[m] = acc;
}

// ---------- MFMA bf16 GEMM v6: 256x128 tile, BK=32, prefetch double-buffer ----------
// Short-K GEMMs (gqkv2, fc1): 24KB LDS keeps multiple blocks/CU (R14 lesson:
// deep buffer only wins at high trip count, i.e. fc2's K=1024).
__global__ __launch_bounds__(512)
void gemm_bt6(const u16* __restrict__ A, int lda,
              const u16* __restrict__ WT,
              const float* __restrict__ bias, u16* __restrict__ C,
              int K, int M, int relu)
{
    __shared__ u16 As0[256 * 32];
    __shared__ u16 As1[256 * 32];
    __shared__ u16 Bs0[128 * 32];
    __shared__ u16 Bs1[128 * 32];
    const int tid  = threadIdx.x;
    const int wid  = tid >> 6;          // 0..7
    const int lane = tid & 63;
    const int l16  = lane & 15;
    const int kg   = lane >> 4;

    const int nwg = gridDim.x * gridDim.y;
    int lin = blockIdx.y * gridDim.x + blockIdx.x;
    lin = (lin & 7) * (nwg >> 3) + (lin >> 3);
    const int row0 = (lin / gridDim.x) * 256;
    const int col0 = (lin % gridDim.x) * 128;

    const int srow = lane >> 2;
    const int gchunk = ((lane & 3) ^ ((srow >> 1) & 3)) * 8;  // inverse-swizzled source
    const int rchunk = (kg ^ ((l16 >> 1) & 3)) * 8;           // swizzled read

    const u16* Abase = A  + (size_t)(row0 + srow) * lda + gchunk;
    const u16* Bbase = WT + (size_t)(col0 + wid * 16 + srow) * K + gchunk;

    f32x4 acc[2][8];
    #pragma unroll
    for (int fr = 0; fr < 2; fr++)
        #pragma unroll
        for (int fc = 0; fc < 8; fc++)
            acc[fr][fc] = (f32x4){0.f, 0.f, 0.f, 0.f};

#define STAGE_T(ASB, BSB, k0)                                                   \
    do {                                                                        \
        _Pragma("unroll")                                                       \
        for (int q = 0; q < 2; q++) {                                           \
            const int rbase = wid * 32 + q * 16;                                \
            gl16(Abase + (size_t)rbase * lda + (k0), &ASB[rbase * 32]);         \
        }                                                                       \
        gl16(Bbase + (k0), &BSB[wid * 16 * 32]);                                \
    } while (0)

#define COMPUTE_T(ASB, BSB)                                                     \
    do {                                                                        \
        bf16x8 af[2], bfr[8];                                                   \
        _Pragma("unroll")                                                       \
        for (int fr = 0; fr < 2; fr++)                                          \
            af[fr] = *(const bf16x8*)(&ASB[(wid * 32 + fr * 16 + l16) * 32 + rchunk]); \
        _Pragma("unroll")                                                       \
        for (int fc = 0; fc < 8; fc++)                                          \
            bfr[fc] = *(const bf16x8*)(&BSB[(fc * 16 + l16) * 32 + rchunk]);    \
        _Pragma("unroll")                                                       \
        for (int fr = 0; fr < 2; fr++)                                          \
            _Pragma("unroll")                                                   \
            for (int fc = 0; fc < 8; fc++)                                      \
                acc[fr][fc] = __builtin_amdgcn_mfma_f32_16x16x32_bf16(af[fr], bfr[fc], acc[fr][fc], 0, 0, 0); \
    } while (0)

    STAGE_T(As0, Bs0, 0);
    __syncthreads();                       // implicit vmcnt(0): tile 0 ready

    for (int k0 = 0; k0 < K; k0 += 64) {
        if (k0 + 32 < K) STAGE_T(As1, Bs1, k0 + 32);
        COMPUTE_T(As0, Bs0);
        __syncthreads();
        if (k0 + 64 < K) STAGE_T(As0, Bs0, k0 + 64);
        COMPUTE_T(As1, Bs1);
        __syncthreads();
    }
#undef STAGE_T

    #pragma unroll
    for (int fr = 0; fr < 2; fr++) {
        #pragma unroll
        for (int fc = 0; fc < 8; fc++) {
            const int col = col0 + fc * 16 + l16;
            const float bv = bias[col];
            const int row = row0 + wid * 32 + fr * 16 + kg * 4;
            #pragma unroll
            for (int j = 0; j < 4; j += 2) {
                float x0 = acc[fr][fc][j]     + bv;
                float x1 = acc[fr][fc][j + 1] + bv;
                if (relu) { x0 = fmaxf(x0, 0.f); x1 = fmaxf(x1, 0.f); }
                const u32 pk = cvtpk2(x0, x1);
                C[(size_t)(row + j)     * M + col] = (u16)pk;
                C[(size_t)(row + j + 1) * M + col] = (u16)(pk >> 16);
            }
        }
    }
#undef COMPUTE_T
}

// ---------- GEMM v6f: f32-A variant (gqkv1) -- converts x during staging ----------
// Replaces the separate cvt_bf16 pass (96MB + a dispatch). A-path: reg-stage
// 8 floats/lane, cvtpk2 (same RNE as cvt_bf16 -> bitwise-identical A tiles),
// ds_write 16B/lane to the EXACT gl16 layout (base + lane*16B). T14 split:
// loads issue at stage point, ds_write deferred until after COMPUTE (previous
// iteration's barrier guarantees target buffer is no longer being read).
__global__ __launch_bounds__(512)
void gemm_bt6f(const float* __restrict__ A, int lda,
               const u16* __restrict__ WT,
               const float* __restrict__ bias, u16* __restrict__ C,
               int K, int M, int relu)
{
    __shared__ u16 As0[256 * 32];
    __shared__ u16 As1[256 * 32];
    __shared__ u16 Bs0[128 * 32];
    __shared__ u16 Bs1[128 * 32];
    const int tid  = threadIdx.x;
    const int wid  = tid >> 6;          // 0..7
    const int lane = tid & 63;
    const int l16  = lane & 15;
    const int kg   = lane >> 4;

    const int nwg = gridDim.x * gridDim.y;
    int lin = blockIdx.y * gridDim.x + blockIdx.x;
    lin = (lin & 7) * (nwg >> 3) + (lin >> 3);
    const int row0 = (lin / gridDim.x) * 256;
    const int col0 = (lin % gridDim.x) * 128;

    const int srow = lane >> 2;
    const int gchunk = ((lane & 3) ^ ((srow >> 1) & 3)) * 8;
    const int rchunk = (kg ^ ((l16 >> 1) & 3)) * 8;

    const float* Abase = A + (size_t)(row0 + srow) * lda + gchunk;
    const u16*   Bbase = WT + (size_t)(col0 + wid * 16 + srow) * K + gchunk;

    f32x4 acc[2][8];
    #pragma unroll
    for (int fr = 0; fr < 2; fr++)
        #pragma unroll
        for (int fc = 0; fc < 8; fc++)
            acc[fr][fc] = (f32x4){0.f, 0.f, 0.f, 0.f};

    float ar[2][8];                      // in-flight A slab (f32)

#define LOADA_F(k0)                                                             \
    do {                                                                        \
        _Pragma("unroll")                                                       \
        for (int q = 0; q < 2; q++) {                                           \
            const float* ga = Abase + (size_t)(wid * 32 + q * 16) * lda + (k0); \
            *(float4*)&ar[q][0] = *(const float4*)(ga);                         \
            *(float4*)&ar[q][4] = *(const float4*)(ga + 4);                     \
        }                                                                       \
    } while (0)

#define WRITEA_F(ASB)                                                           \
    do {                                                                        \
        _Pragma("unroll")                                                       \
        for (int q = 0; q < 2; q++) {                                           \
            const int rbase = wid * 32 + q * 16;                                \
            *(uint4*)&ASB[rbase * 32 + lane * 8] = pack8bf(ar[q]);              \
        }                                                                       \
    } while (0)

#define STAGEB_F(BSB, k0) gl16(Bbase + (k0), &BSB[wid * 16 * 32])

#define COMPUTE_F(ASB, BSB)                                                     \
    do {                                                                        \
        bf16x8 af[2], bfr[8];                                                   \
        _Pragma("unroll")                                                       \
        for (int fr = 0; fr < 2; fr++)                                          \
            af[fr] = *(const bf16x8*)(&ASB[(wid * 32 + fr * 16 + l16) * 32 + rchunk]); \
        _Pragma("unroll")                                                       \
        for (int fc = 0; fc < 8; fc++)                                          \
            bfr[fc] = *(const bf16x8*)(&BSB[(fc * 16 + l16) * 32 + rchunk]);    \
        _Pragma("unroll")                                                       \
        for (int fr = 0; fr < 2; fr++)                                          \
            _Pragma("unroll")                                                   \
            for (int fc = 0; fc < 8; fc++)                                      \
                acc[fr][fc] = __builtin_amdgcn_mfma_f32_16x16x32_bf16(af[fr], bfr[fc], acc[fr][fc], 0, 0, 0); \
    } while (0)

    LOADA_F(0);
    STAGEB_F(Bs0, 0);
    WRITEA_F(As0);
    __syncthreads();

    for (int k0 = 0; k0 < K; k0 += 64) {
        if (k0 + 32 < K) { LOADA_F(k0 + 32); STAGEB_F(Bs1, k0 + 32); }
        COMPUTE_F(As0, Bs0);
        if (k0 + 32 < K) WRITEA_F(As1);    // safe: prev iter's barrier drained As1 readers
        __syncthreads();
        if (k0 + 64 < K) { LOADA_F(k0 + 64); STAGEB_F(Bs0, k0 + 64); }
        COMPUTE_F(As1, Bs1);
        if (k0 + 64 < K) WRITEA_F(As0);
        __syncthreads();
    }
#undef LOADA_F
#undef WRITEA_F
#undef STAGEB_F
#undef COMPUTE_F

    #pragma unroll
    for (int fr = 0; fr < 2; fr++) {
        #pragma unroll
        for (int fc = 0; fc < 8; fc++) {
            const int col = col0 + fc * 16 + l16;
            const float bv = bias[col];
            const int row = row0 + wid * 32 + fr * 16 + kg * 4;
            #pragma unroll
            for (int j = 0; j < 4; j += 2) {
                float x0 = acc[fr][fc][j]     + bv;
                float x1 = acc[fr][fc][j + 1] + bv;
                if (relu) { x0 = fmaxf(x0, 0.f); x1 = fmaxf(x1, 0.f); }
                const u32 pk = cvtpk2(x0, x1);
                C[(size_t)(row + j)     * M + col] = (u16)pk;
                C[(size_t)(row + j + 1) * M + col] = (u16)(pk >> 16);
            }
        }
    }
}

// ---------- GEMM + residual + LN fused, 256x256, BK=64 dbuf (gd+ln1, fc2+ln2) ----------
template<typename TR, typename TO>
__global__ __launch_bounds__(512)
void gemm_ln2(const u16* __restrict__ A, int lda,
              const u16* __restrict__ WT,
              const float* __restrict__ bias,
              const TR* __restrict__ R,
              const float* __restrict__ gw, const float* __restrict__ bw,
              TO* __restrict__ out, int K)
{
    __shared__ u16 As0a[256 * 32];
    __shared__ u16 As0b[256 * 32];
    __shared__ u16 As1a[256 * 32];
    __shared__ u16 As1b[256 * 32];
    __shared__ u16 Bs0a[256 * 32];
    __shared__ u16 Bs0b[256 * 32];
    __shared__ u16 Bs1a[256 * 32];
    __shared__ u16 Bs1b[256 * 32];
    const int tid  = threadIdx.x;
    const int wid  = tid >> 6;          // 0..7
    const int lane = tid & 63;
    const int l16  = lane & 15;
    const int kg   = lane >> 4;

    const int nwg = gridDim.x;          // must be %8==0
    int lin = blockIdx.x;
    lin = (lin & 7) * (nwg >> 3) + (lin >> 3);
    const int row0 = lin * 256;

    const int srow = lane >> 2;
    const int gchunk = ((lane & 3) ^ ((srow >> 1) & 3)) * 8;
    const int rchunk = (kg ^ ((l16 >> 1) & 3)) * 8;

    const u16* Abase = A  + (size_t)(row0 + wid * 32 + srow) * lda + gchunk;
    const u16* Bbase = WT + (size_t)(wid * 32 + srow) * K + gchunk;

    f32x4 acc[2][16];
    #pragma unroll
    for (int fr = 0; fr < 2; fr++)
        #pragma unroll
        for (int fc = 0; fc < 16; fc++)
            acc[fr][fc] = (f32x4){0.f, 0.f, 0.f, 0.f};

#define STAGE_L2(ASA, ASB2, BSA, BSB2, k0)                                      \
    do {                                                                        \
        _Pragma("unroll")                                                       \
        for (int q = 0; q < 2; q++) {                                           \
            const int rbase = wid * 32 + q * 16;                                \
            gl16(Abase + (size_t)(q * 16) * lda + (k0),      &ASA[rbase * 32]); \
            gl16(Abase + (size_t)(q * 16) * lda + (k0) + 32, &ASB2[rbase * 32]);\
            gl16(Bbase + (size_t)(q * 16) * K   + (k0),      &BSA[rbase * 32]); \
            gl16(Bbase + (size_t)(q * 16) * K   + (k0) + 32, &BSB2[rbase * 32]);\
        }                                                                       \
    } while (0)

#define COMPUTE_L2(ASB, BSB)                                                    \
    do {                                                                        \
        bf16x8 af[2];                                                           \
        _Pragma("unroll")                                                       \
        for (int fr = 0; fr < 2; fr++)                                          \
            af[fr] = *(const bf16x8*)(&ASB[(wid * 32 + fr * 16 + l16) * 32 + rchunk]); \
        _Pragma("unroll")                                                       \
        for (int fc = 0; fc < 16; fc++) {                                       \
            bf16x8 bfr = *(const bf16x8*)(&BSB[(fc * 16 + l16) * 32 + rchunk]); \
            acc[0][fc] = __builtin_amdgcn_mfma_f32_16x16x32_bf16(af[0], bfr, acc[0][fc], 0, 0, 0); \
            acc[1][fc] = __builtin_amdgcn_mfma_f32_16x16x32_bf16(af[1], bfr, acc[1][fc], 0, 0, 0); \
        }                                                                       \
    } while (0)

    STAGE_L2(As0a, As0b, Bs0a, Bs0b, 0);
    __syncthreads();

    for (int k0 = 0; k0 < K; k0 += 128) {
        if (k0 + 64 < K) STAGE_L2(As1a, As1b, Bs1a, Bs1b, k0 + 64);
        COMPUTE_L2(As0a, Bs0a);
        COMPUTE_L2(As0b, Bs0b);
        __syncthreads();
        if (k0 + 128 < K) STAGE_L2(As0a, As0b, Bs0a, Bs0b, k0 + 128);
        COMPUTE_L2(As1a, Bs1a);
        COMPUTE_L2(As1b, Bs1b);
        __syncthreads();
    }
#undef STAGE_L2
#undef COMPUTE_L2

    float bia[16], gwv[16], bwv[16];
    #pragma unroll
    for (int fc = 0; fc < 16; fc++) {
        const int d = fc * 16 + l16;
        bia[fc] = bias[d]; gwv[fc] = gw[d]; bwv[fc] = bw[d];
    }
    #pragma unroll
    for (int fr = 0; fr < 2; fr++) {
        #pragma unroll
        for (int j = 0; j < 4; j++) {
            const int row = row0 + wid * 32 + fr * 16 + kg * 4 + j;
            const size_t rb = (size_t)row * DD + l16;
            float v[16];
            float s1 = 0.f, s2 = 0.f;
            #pragma unroll
            for (int fc = 0; fc < 16; fc++) {
                const float xv = acc[fr][fc][j] + bia[fc] + rload(R + rb + fc * 16);
                v[fc] = xv; s1 += xv; s2 += xv * xv;
            }
            #pragma unroll
            for (int o = 1; o < 16; o <<= 1) { s1 += __shfl_xor(s1, o); s2 += __shfl_xor(s2, o); }
            const float mean = s1 * (1.f / DD);
            const float var  = s2 * (1.f / DD) - mean * mean;
            const float rs   = rsqrtf(var + EPSV);
            #pragma unroll
            for (int fc = 0; fc < 16; fc++)
                sstore(out + rb + fc * 16, (v[fc] - mean) * rs * gwv[fc] + bwv[fc]);
        }
    }
}

// ---------- time attention v12: in-register P + MFMA row sums + pair cvt ----------
__global__ __launch_bounds__(256)
void time_attn12(const u16* __restrict__ F, int ld, u16* __restrict__ O)
{
    __shared__ u16 Ks2[2][64 * KP];
    __shared__ u16 Vt2[2][32 * VP6];
    const int bid = blockIdx.x;
    const int tid  = threadIdx.x;
    const int wid  = tid >> 6;
    const int lane = tid & 63;
    const int l16  = lane & 15;
    const int g    = lane >> 4;

    #pragma unroll
    for (int it = 0; it < 2; it++) {
        const int i = tid + it * 256;
        const int tu = i >> 8, rr = (i >> 2) & 63, p = i & 3;
        const int tau = bid * 2 + tu;
        const size_t ga = ((size_t)(tau >> 3) * 64 + rr) * ld + (tau & 7) * DKK + 256 + p * 8;
        *(uint4*)&Ks2[tu][rr * KP + p * 8] = *(const uint4*)(F + ga);
    }
    #pragma unroll
    for (int it = 0; it < 2; it++) {
        const int i = tid + it * 256;
        const int tu = i >> 8, p = (i >> 6) & 3, rr = i & 63;
        const int tau = bid * 2 + tu;
        const size_t ga = ((size_t)(tau >> 3) * 64 + rr) * ld + (tau & 7) * DKK + 512 + p * 8;
        uint4 vv = *(const uint4*)(F + ga);
        const u16* vp = (const u16*)&vv;
        #pragma unroll
        for (int j = 0; j < 8; j++) Vt2[tu][(p * 8 + j) * VP6 + rr] = vp[j];
    }
    __syncthreads();

    const int tu  = wid >> 1;
    const int tau = bid * 2 + tu;
    const int hc  = (tau & 7) * DKK;
    const size_t n0 = (size_t)(tau >> 3) * 64;
    const int q0  = (wid & 1) * 32;
    const f32x4 z4 = (f32x4){0.f, 0.f, 0.f, 0.f};
    const bf16x4 vone = (bf16x4){BF16_ONE, BF16_ONE, BF16_ONE, BF16_ONE};

    bf16x8 qf[2];
    #pragma unroll
    for (int f = 0; f < 2; f++)
        qf[f] = *(const bf16x8*)(F + (n0 + q0 + f * 16 + l16) * ld + hc + g * 8);

    f32x4 s[2][4];
    #pragma unroll
    for (int kt = 0; kt < 4; kt++) {
        bf16x8 kf = *(const bf16x8*)&Ks2[tu][(kt * 16 + l16) * KP + g * 8];
        s[0][kt] = __builtin_amdgcn_mfma_f32_16x16x32_bf16(kf, qf[0], z4, 0, 0, 0);
        s[1][kt] = __builtin_amdgcn_mfma_f32_16x16x32_bf16(kf, qf[1], z4, 0, 0, 0);
    }

    bf16x4 pp[2][4];
    #pragma unroll
    for (int f = 0; f < 2; f++) {
        #pragma unroll
        for (int kt = 0; kt < 4; kt++) {
            float pv[4];
            #pragma unroll
            for (int j = 0; j < 4; j++) pv[j] = EXP2(s[f][kt][j]);
            pp[f][kt] = packbf4(pv);
        }
    }

    f32x4 o[2][2];
    f32x4 lacc[2];
    #pragma unroll
    for (int f = 0; f < 2; f++) {
        lacc[f] = z4;
        #pragma unroll
        for (int hh = 0; hh < 2; hh++)
            o[f][hh] = z4;
    }
    #pragma unroll
    for (int kt = 0; kt < 4; kt++) {
        bf16x4 vf[2];
        #pragma unroll
        for (int hh = 0; hh < 2; hh++)
            vf[hh] = *(const bf16x4*)&Vt2[tu][(hh * 16 + l16) * VP6 + kt * 16 + g * 4];
        #pragma unroll
        for (int f = 0; f < 2; f++) {
            o[f][0] = mfma16(pp[f][kt], vf[0], o[f][0]);
            o[f][1] = mfma16(pp[f][kt], vf[1], o[f][1]);
            lacc[f] = mfma16(pp[f][kt], vone, lacc[f]);
        }
    }

    #pragma unroll
    for (int f = 0; f < 2; f++) {
        float iv[4];
        #pragma unroll
        for (int j = 0; j < 4; j++) iv[j] = 1.f / lacc[f][j];
        #pragma unroll
        for (int hh = 0; hh < 2; hh++) {
            const u32 p0 = cvtpk2(o[f][hh][0] * iv[0], o[f][hh][1] * iv[1]);
            const u32 p1 = cvtpk2(o[f][hh][2] * iv[2], o[f][hh][3] * iv[3]);
            const size_t ga0 = (n0 + q0 + f * 16 + g * 4) * DD + hc + hh * 16 + l16;  // AO: ld=DD
            O[ga0]          = (u16)p0;
            O[ga0 + DD]     = (u16)(p0 >> 16);
            O[ga0 + 2 * DD] = (u16)p1;
            O[ga0 + 3 * DD] = (u16)(p1 >> 16);
        }
    }
}

// ---------- space attention v16: async dbuf + MFMA row sums + pair cvt + setprio ----------
__global__ __launch_bounds__(512, 4)
void space_attn16(u16* __restrict__ F, int ld)
{
    __shared__ u16 Ks[2][128 * KPS];
    __shared__ u16 Vt[2][32 * VH];
    const int bid = blockIdx.x;             // (b*H + h)*T + t
    const int t  = bid & (TT_ - 1);
    const int h  = (bid >> 6) & (HH - 1);
    const int b  = bid >> 9;
    const int hc = h * DKK;
    const int tid  = threadIdx.x;
    const int wid  = tid >> 6;
    const int lane = tid & 63;
    const int l16  = lane & 15;
    const int g    = lane >> 4;

    const int kr = tid >> 2, kp = tid & 3;
    const int vr = tid & 127, vp = tid >> 7;
    const size_t rowstr = (size_t)TT_ * ld;
    const size_t base0  = ((size_t)(b * SS) * TT_ + t) * ld + hc;

    const int q0 = wid * 64;
    bf16x8 qf[4];
    #pragma unroll
    for (int f = 0; f < 4; f++) {
        const int s = q0 + f * 16 + l16;
        qf[f] = *(const bf16x8*)(F + base0 + (size_t)s * rowstr + g * 8);
    }

    uint4 kreg = *(const uint4*)(F + base0 + 256 + (size_t)kr * rowstr + kp * 8);
    uint4 vreg = *(const uint4*)(F + base0 + 512 + (size_t)vr * rowstr + vp * 8);
    *(uint4*)&Ks[0][kr * KPS + kp * 8] = kreg;
    {
        const u16* vpp = (const u16*)&vreg;
        #pragma unroll
        for (int j = 0; j < 8; j++) Vt[0][(vp * 8 + j) * VH + vr] = vpp[j];
    }
    __syncthreads();

    f32x4 o[4][2];
    f32x4 lacc[4];
    const f32x4 z4 = (f32x4){0.f, 0.f, 0.f, 0.f};
    const bf16x4 vone = (bf16x4){BF16_ONE, BF16_ONE, BF16_ONE, BF16_ONE};
    #pragma unroll
    for (int f = 0; f < 4; f++) {
        lacc[f] = z4;
        #pragma unroll
        for (int hh = 0; hh < 2; hh++)
            o[f][hh] = z4;
    }

    for (int qtr = 0; qtr < 4; qtr++) {
        const int cur = qtr & 1;
        if (qtr < 3) {
            const int key = (qtr + 1) * 128;
            kreg = *(const uint4*)(F + base0 + 256 + (size_t)(key + kr) * rowstr + kp * 8);
            vreg = *(const uint4*)(F + base0 + 512 + (size_t)(key + vr) * rowstr + vp * 8);
        }

        for (int kc2 = 0; kc2 < 4; kc2++) {
            bf16x8 kfa = *(const bf16x8*)&Ks[cur][(kc2 * 32 +      l16) * KPS + g * 8];
            bf16x8 kfb = *(const bf16x8*)&Ks[cur][(kc2 * 32 + 16 + l16) * KPS + g * 8];

            bf16x4 pa[4], pb[4];
            #pragma unroll
            for (int f = 0; f < 4; f++) {
                f32x4 sa = __builtin_amdgcn_mfma_f32_16x16x32_bf16(kfa, qf[f], z4, 0, 0, 0);
                f32x4 sb = __builtin_amdgcn_mfma_f32_16x16x32_bf16(kfb, qf[f], z4, 0, 0, 0);
                float pva[4], pvb[4];
                #pragma unroll
                for (int j = 0; j < 4; j++) pva[j] = EXP2(sa[j]);
                #pragma unroll
                for (int j = 0; j < 4; j++) pvb[j] = EXP2(sb[j]);
                pa[f] = packbf4(pva);
                pb[f] = packbf4(pvb);
            }

            bf16x4 va[2][2];
            #pragma unroll
            for (int hh = 0; hh < 2; hh++)
                #pragma unroll
                for (int u = 0; u < 2; u++)
                    va[hh][u] = *(const bf16x4*)&Vt[cur][(hh * 16 + l16) * VH + kc2 * 32 + u * 16 + g * 4];

            __builtin_amdgcn_s_setprio(1);
            #pragma unroll
            for (int f = 0; f < 4; f++) {
                #pragma unroll
                for (int hh = 0; hh < 2; hh++) {
                    o[f][hh] = mfma16(pa[f], va[hh][0], o[f][hh]);
                    o[f][hh] = mfma16(pb[f], va[hh][1], o[f][hh]);
                }
                lacc[f] = mfma16(pa[f], vone, lacc[f]);
                lacc[f] = mfma16(pb[f], vone, lacc[f]);
            }
            __builtin_amdgcn_s_setprio(0);
        }

        if (qtr < 3) {
            __syncthreads();
            *(uint4*)&Ks[cur ^ 1][kr * KPS + kp * 8] = kreg;
            const u16* vpp = (const u16*)&vreg;
            #pragma unroll
            for (int j = 0; j < 8; j++) Vt[cur ^ 1][(vp * 8 + j) * VH + vr] = vpp[j];
            __syncthreads();
        }
    }

    #pragma unroll
    for (int f = 0; f < 4; f++) {
        float iv[4];
        #pragma unroll
        for (int j = 0; j < 4; j++) iv[j] = 1.f / lacc[f][j];
        const int s = q0 + f * 16 + g * 4;
        #pragma unroll
        for (int hh = 0; hh < 2; hh++) {
            const u32 p0 = cvtpk2(o[f][hh][0] * iv[0], o[f][hh][1] * iv[1]);
            const u32 p1 = cvtpk2(o[f][hh][2] * iv[2], o[f][hh][3] * iv[3]);
            const size_t ga0 = base0 + (size_t)s * rowstr + hh * 16 + l16;
            F[ga0]              = (u16)p0;
            F[ga0 + rowstr]     = (u16)(p0 >> 16);
            F[ga0 + 2 * rowstr] = (u16)p1;
            F[ga0 + 3 * rowstr] = (u16)(p1 >> 16);
        }
    }
}

// ---------- residual add + LayerNorm (fallback path) ----------
template<typename T1, typename TO>
__global__ __launch_bounds__(256)
void add_ln(const T1* __restrict__ X1, const u16* __restrict__ X2,
            const float* __restrict__ gw, const float* __restrict__ bw,
            TO* __restrict__ out)
{
    const int row  = blockIdx.x * 4 + (threadIdx.x >> 6);
    const int lane = threadIdx.x & 63;
    const size_t base = (size_t)row * DD + lane * 4;
    float v[4], w2[4];
    load4v(X1 + base, v);
    load4v(X2 + base, w2);
    v[0] += w2[0]; v[1] += w2[1]; v[2] += w2[2]; v[3] += w2[3];
    float s1 = v[0] + v[1] + v[2] + v[3];
    float s2 = v[0]*v[0] + v[1]*v[1] + v[2]*v[2] + v[3]*v[3];
    #pragma unroll
    for (int o = 1; o < 64; o <<= 1) { s1 += __shfl_xor(s1, o); s2 += __shfl_xor(s2, o); }
    const float mean = s1 * (1.f / DD);
    const float var  = s2 * (1.f / DD) - mean * mean;
    const float rs   = rsqrtf(var + EPSV);
    float o4[4];
    #pragma unroll
    for (int i = 0; i < 4; i++) {
        const int d = lane * 4 + i;
        o4[i] = (v[i] - mean) * rs * gw[d] + bw[d];
    }
    store4o(out + base, o4);
}

// ---------- MFMA bf16 GEMM v6h: 128x128 tile variant (fallback fc2) ----------
__global__ __launch_bounds__(512)
void gemm_bt6h(const u16* __restrict__ A, int lda,
               const u16* __restrict__ WT,
               const float* __restrict__ bias, u16* __restrict__ C,
               int K, int M, int relu)
{
    __shared__ u16 As0[128 * 32];
    __shared__ u16 As1[128 * 32];
    __shared__ u16 Bs0[128 * 32];
    __shared__ u16 Bs1[128 * 32];
    const int tid  = threadIdx.x;
    const int wid  = tid >> 6;          // 0..7
    const int lane = tid & 63;
    const int l16  = lane & 15;
    const int kg   = lane >> 4;

    const int nwg = gridDim.x * gridDim.y;
    int lin = blockIdx.y * gridDim.x + blockIdx.x;
    lin = (lin & 7) * (nwg >> 3) + (lin >> 3);
    const int row0 = (lin / gridDim.x) * 128;
    const int col0 = (lin % gridDim.x) * 128;

    const int srow = lane >> 2;
    const int gchunk = ((lane & 3) ^ ((srow >> 1) & 3)) * 8;
    const int rchunk = (kg ^ ((l16 >> 1) & 3)) * 8;

    const u16* Abase = A  + (size_t)(row0 + wid * 16 + srow) * lda + gchunk;
    const u16* Bbase = WT + (size_t)(col0 + wid * 16 + srow) * K + gchunk;

    f32x4 acc[8];
    #pragma unroll
    for (int fc = 0; fc < 8; fc++)
        acc[fc] = (f32x4){0.f, 0.f, 0.f, 0.f};

#define STAGE_H(ASB, BSB, k0)                                                   \
    do {                                                                        \
        gl16(Abase + (k0), &ASB[wid * 16 * 32]);                                \
        gl16(Bbase + (k0), &BSB[wid * 16 * 32]);                                \
    } while (0)

#define COMPUTE_H(ASB, BSB)                                                     \
    do {                                                                        \
        bf16x8 af, bfr[8];                                                      \
        af = *(const bf16x8*)(&ASB[(wid * 16 + l16) * 32 + rchunk]);            \
        _Pragma("unroll")                                                       \
        for (int fc = 0; fc < 8; fc++)                                          \
            bfr[fc] = *(const bf16x8*)(&BSB[(fc * 16 + l16) * 32 + rchunk]);    \
        _Pragma("unroll")                                                       \
        for (int fc = 0; fc < 8; fc++)                                          \
            acc[fc] = __builtin_amdgcn_mfma_f32_16x16x32_bf16(af, bfr[fc], acc[fc], 0, 0, 0); \
    } while (0)

    STAGE_H(As0, Bs0, 0);
    __syncthreads();

    for (int k0 = 0; k0 < K; k0 += 64) {
        if (k0 + 32 < K) STAGE_H(As1, Bs1, k0 + 32);
        COMPUTE_H(As0, Bs0);
        __syncthreads();
        if (k0 + 64 < K) STAGE_H(As0, Bs0, k0 + 64);
        COMPUTE_H(As1, Bs1);
        __syncthreads();
    }
#undef STAGE_H
#undef COMPUTE_H

    #pragma unroll
    for (int fc = 0; fc < 8; fc++) {
        const int col = col0 + fc * 16 + l16;
        const float bv = bias[col];
        const int row = row0 + wid * 16 + kg * 4;
        #pragma unroll
        for (int j = 0; j < 4; j += 2) {
            float x0 = acc[fc][j]     + bv;
            float x1 = acc[fc][j + 1] + bv;
            if (relu) { x0 = fmaxf(x0, 0.f); x1 = fmaxf(x1, 0.f); }
            const u32 pk = cvtpk2(x0, x1);
            C[(size_t)(row + j)     * M + col] = (u16)pk;
            C[(size_t)(row + j + 1) * M + col] = (u16)(pk >> 16);
        }
    }
}

// ---------- launch ----------
extern "C" void kernel_launch(void* const* d_in, const int* in_sizes, int n_in,
                              void* d_out, int out_size, void* d_ws, size_t ws_size,
                              hipStream_t stream)
{
    (void)in_sizes; (void)n_in; (void)out_size;
    const float* x     = (const float*)d_in[0];
    const float* tq_w  = (const float*)d_in[1];
    const float* tq_b  = (const float*)d_in[2];
    const float* tk_w  = (const float*)d_in[3];
    const float* tk_b  = (const float*)d_in[4];
    const float* tv_w  = (const float*)d_in[5];
    const float* tv_b  = (const float*)d_in[6];
    const float* to_w  = (const float*)d_in[7];
    const float* to_b  = (const float*)d_in[8];
    const float* sq_w  = (const float*)d_in[9];
    const float* sq_b  = (const float*)d_in[10];
    const float* sk_w  = (const float*)d_in[11];
    const float* sk_b  = (const float*)d_in[12];
    const float* sv_w  = (const float*)d_in[13];
    const float* sv_b  = (const float*)d_in[14];
    const float* so_w  = (const float*)d_in[15];
    const float* so_b  = (const float*)d_in[16];
    const float* fc1_w = (const float*)d_in[17];
    const float* fc1_b = (const float*)d_in[18];
    const float* fc2_w = (const float*)d_in[19];
    const float* fc2_b = (const float*)d_in[20];
    const float* ln1_w = (const float*)d_in[21];
    const float* ln1_b = (const float*)d_in[22];
    const float* ln2_w = (const float*)d_in[23];
    const float* ln2_b = (const float*)d_in[24];

    const size_t SLOT = (size_t)NTOK * DD;   // elems (33.5 MB as u16)
    u16*   F  = (u16*)d_ws;                  // fused [N][768] activations = slots 0-2
    u16*   OA = (u16*)d_out;                 // bf16 scratch: AO (first writer = time_attn)
    float* HD = (float*)d_out;               // f32 final output

    // ffn1 layout (ws >= 6 slots): F 0-2 | W1FF 0-3 (F dead) | WTb slot 4 | HB slot 5
    const bool ffn1 = ws_size >= 6 * SLOT * sizeof(u16);
    u16*   WTb = ffn1 ? ((u16*)d_ws + 4 * SLOT)
                      : (u16*)((char*)d_out + (61u << 20));
    float* BIb = ffn1 ? (float*)((u16*)d_ws + 4 * SLOT + 983040)
                      : (float*)((char*)d_out + (63u << 20));

    u16* wt_tqkv  = WTb;                     // [768][256]
    u16* wt_fused = wt_tqkv + 3 * 65536;     // fused to*sqkv [768][256]
    u16* wt_so    = wt_fused + 3 * 65536;
    u16* wt_fc1   = wt_so + 65536;
    u16* wt_fc2   = wt_fc1 + 262144;         // ends at elem 983040 (1.92MB)
    float* b_tqkv  = BIb;                    // 768
    float* b_fused = BIb + 768;              // 768

    dim3 blk(256);
    dim3 blk5(512);

    // 4 square transposes in ONE dispatch (z-indexed); fc1/fc2 separate shapes
    transpose_w4<<<dim3(DD / 32, DD / 32, 4), blk, 0, stream>>>(
        tq_w, tk_w, tv_w, so_w,
        wt_tqkv, wt_tqkv + 65536, wt_tqkv + 2 * 65536, wt_so, S2F);
    transpose_w<<<dim3(FFF / 32, DD / 32), blk, 0, stream>>>(fc1_w, wt_fc1, DD, FFF, 1.0f);
    transpose_w<<<dim3(DD / 32, FFF / 32), blk, 0, stream>>>(fc2_w, wt_fc2, FFF, DD, 1.0f);
    pack_bias3<<<1, blk, 0, stream>>>(tq_b, tk_b, tv_b, b_tqkv, S2F);
    fuse_to_sqkv_w<<<768, blk, 0, stream>>>(to_w, sq_w, sk_w, sv_w, wt_fused);
    fuse_to_sqkv_b<<<3, blk, 0, stream>>>(to_b, sq_w, sk_w, sv_w, sq_b, sk_b, sv_b, b_fused);

    // 256-row tiles: grids (cols, rows/256); all nwg % 8 == 0 for XCD swizzle
    dim3 gqkv(768 / 128, NTOK / 256);        // (6, 256) = 1536

    // ---- time attention: QKV from f32 x (cvt fused into staging) -> F; AO -> OA ----
    gemm_bt6f<<<gqkv, blk5, 0, stream>>>(x, DD, wt_tqkv, b_tqkv, F, DD, 768, 0);
    time_attn12<<<BB * HH * SS / 2, blk, 0, stream>>>(F, 768, OA);

    // ---- space attention: fused (to*sqkv) projection AO -> F; attn in-place ----
    gemm_bt6<<<gqkv, blk5, 0, stream>>>(OA, DD, wt_fused, b_fused, F, DD, 768, 0);
    space_attn16<<<BB * HH * TT_, blk5, 0, stream>>>(F, 768);

    if (ffn1) {
        u16* HB   = (u16*)d_ws + 5 * SLOT;   // h = LN1(x + so), slot 5
        u16* W1FF = (u16*)d_ws;              // FFN intermediate, slots 0-3 (F dead after gd_ln)
        // gd + ln1 fused (256x256 BK=64, K=256): reads F (slots 0-2) + x -> HB (slot 5)
        gemm_ln2<float, u16><<<NTOK / 256, blk5, 0, stream>>>(
            F, 768, wt_so, so_b, x, ln1_w, ln1_b, HB, DD);
        // fc1 (256x128 BK=32, multi-block/CU): reads HB (slot 5), writes W1FF (slots 0-3)
        gemm_bt6<<<dim3(FFF / 128, NTOK / 256), blk5, 0, stream>>>(
            HB, DD, wt_fc1, fc1_b, W1FF, DD, FFF, 1);
        // fc2 + ln2 fused (256x256 BK=64, K=1024): W1FF (0-3) + HB (5) + wt (4) -> HD
        gemm_ln2<u16, float><<<NTOK / 256, blk5, 0, stream>>>(
            W1FF, FFF, wt_fc2, fc2_b, HB, ln2_w, ln2_b, HD, FFF);
    } else {
        // ---- fallback: R9-style path (weights in d_out; add_ln separate dispatches) ----
        u16* W0 = (u16*)d_ws;
        u16* W1 = W0 + SLOT;
        u16* W2 = W1 + SLOT;
        dim3 gd(DD / 128, NTOK / 256);
        gemm_bt6<<<gd, blk5, 0, stream>>>(F, 768, wt_so, so_b, OA, DD, DD, 0);
        add_ln<float, u16><<<NTOK / 4, blk, 0, stream>>>(x, OA, ln1_w, ln1_b, W0);
        for (int c = 0; c < 4; c++) {
            const size_t off = (size_t)c * 16384 * DD;
            gemm_bt6<<<dim3(FFF / 128, 16384 / 256), blk5, 0, stream>>>(W0 + off, DD, wt_fc1, fc1_b, W1, DD, FFF, 1);
            gemm_bt6h<<<dim3(DD / 128, 16384 / 128), blk5, 0, stream>>>(W1, FFF, wt_fc2, fc2_b, W2, FFF, DD, 0);
            add_ln<u16, float><<<16384 / 4, blk, 0, stream>>>(W0 + off, W2, ln2_w, ln2_b, HD + off);
        }
    }
}

// Round 17
// 382.753 us; speedup vs baseline: 1.1038x; 1.1038x over previous
//
#include <hip/hip_runtime.h>
#include <hip/hip_bf16.h>

// Problem constants
#define BB   2
#define SS   512
#define TT_  64
#define DD   256
#define HH   8
#define DKK  32
#define FFF  1024
#define NTOK 65536           // B*S*T
#define EPSV 1e-5f
#define SCALE 0.17677669529663687f   // 1/sqrt(32)
#define S2F   0.25503486f            // SCALE * log2(e): folded into Q projection
#define KPS  40              // space_attn K row stride (80B rows, proven)
#define KP   40              // time_attn K stride
#define VH   136             // space Vt row stride (272B)
#define VP6  80              // time_attn Vt row stride

typedef unsigned short u16;
typedef unsigned int   u32;
typedef __attribute__((ext_vector_type(8))) short bf16x8;
typedef __attribute__((ext_vector_type(4))) short bf16x4;
typedef __attribute__((ext_vector_type(4))) float f32x4;

#if __has_builtin(__builtin_amdgcn_exp2f)
#define EXP2(x) __builtin_amdgcn_exp2f(x)
#else
#define EXP2(x) exp2f(x)
#endif

// ---------- helpers ----------
__device__ __forceinline__ float bf2f(u32 u) {
    union { u32 i; float f; } c; c.i = u << 16; return c.f;
}
__device__ __forceinline__ u16 f2bf(float f) {
    __hip_bfloat16 h = __float2bfloat16(f);
    return *reinterpret_cast<u16*>(&h);
}
__device__ __forceinline__ u32 cvtpk2(float lo, float hi) {
    float2 f; f.x = lo; f.y = hi;
    __hip_bfloat162 h2 = __float22bfloat162_rn(f);
    union { __hip_bfloat162 h; u32 u; } c; c.h = h2;
    return c.u;
}
__device__ __forceinline__ void load8v(const float* p, float* v) {
    *(float4*)(v)     = *(const float4*)(p);
    *(float4*)(v + 4) = *(const float4*)(p + 4);
}
__device__ __forceinline__ void load8v(const u16* p, float* v) {
    uint4 raw = *(const uint4*)(p);
    v[0] = bf2f(raw.x & 0xffffu); v[1] = bf2f(raw.x >> 16);
    v[2] = bf2f(raw.y & 0xffffu); v[3] = bf2f(raw.y >> 16);
    v[4] = bf2f(raw.z & 0xffffu); v[5] = bf2f(raw.z >> 16);
    v[6] = bf2f(raw.w & 0xffffu); v[7] = bf2f(raw.w >> 16);
}
__device__ __forceinline__ void load4v(const float* p, float* v) {
    float4 t = *(const float4*)p; v[0] = t.x; v[1] = t.y; v[2] = t.z; v[3] = t.w;
}
__device__ __forceinline__ void load4v(const u16* p, float* v) {
    uint2 raw = *(const uint2*)p;
    v[0] = bf2f(raw.x & 0xffffu); v[1] = bf2f(raw.x >> 16);
    v[2] = bf2f(raw.y & 0xffffu); v[3] = bf2f(raw.y >> 16);
}
__device__ __forceinline__ uint4 pack8bf(const float* v) {
    uint4 r;
    r.x = cvtpk2(v[0], v[1]); r.y = cvtpk2(v[2], v[3]);
    r.z = cvtpk2(v[4], v[5]); r.w = cvtpk2(v[6], v[7]);
    return r;
}
__device__ __forceinline__ uint2 pack4bf(const float* v) {
    uint2 r;
    r.x = cvtpk2(v[0], v[1]); r.y = cvtpk2(v[2], v[3]);
    return r;
}
__device__ __forceinline__ bf16x4 packbf4(const float* v) {
    union { uint2 u; bf16x4 h; } c;
    c.u = pack4bf(v);
    return c.h;
}
__device__ __forceinline__ void store4o(float* p, const float* v) {
    float4 t; t.x = v[0]; t.y = v[1]; t.z = v[2]; t.w = v[3];
    *(float4*)p = t;
}
__device__ __forceinline__ void store4o(u16* p, const float* v) {
    *(uint2*)p = pack4bf(v);
}
__device__ __forceinline__ float rload(const float* p) { return *p; }
__device__ __forceinline__ float rload(const u16* p)  { return bf2f(*p); }
__device__ __forceinline__ void sstore(float* p, float v) { *p = v; }
__device__ __forceinline__ void sstore(u16* p, float v)   { *p = f2bf(v); }
__device__ __forceinline__ void gl16(const u16* gsrc, u16* ldst) {
    __builtin_amdgcn_global_load_lds(
        (const __attribute__((address_space(1))) void*)gsrc,
        (__attribute__((address_space(3))) void*)ldst, 16, 0, 0);
}

#if __has_builtin(__builtin_amdgcn_mfma_f32_16x16x16bf16_1k)
__device__ __forceinline__ f32x4 mfma16(bf16x4 a, bf16x4 b, f32x4 c) {
    return __builtin_amdgcn_mfma_f32_16x16x16bf16_1k(a, b, c, 0, 0, 0);
}
#else
__device__ __forceinline__ f32x4 mfma16(bf16x4 a, bf16x4 b, f32x4 c) {
    asm("v_mfma_f32_16x16x16_bf16 %0, %1, %2, %0" : "+v"(c) : "v"(a), "v"(b));
    return c;
}
#endif

#define BF16_ONE ((short)0x3F80)

// ---------- weight transpose: WT[m][k] = bf16(W[k][m] * scale) ----------
__global__ __launch_bounds__(256)
void transpose_w(const float* __restrict__ W, u16* __restrict__ WT, int K, int M,
                 float scale)
{
    __shared__ float t[32][33];
    const int mb = blockIdx.x * 32;
    const int kb = blockIdx.y * 32;
    const int lx = threadIdx.x & 31;
    const int ly = threadIdx.x >> 5;
    #pragma unroll
    for (int i = ly; i < 32; i += 8) t[i][lx] = W[(size_t)(kb + i) * M + mb + lx];
    __syncthreads();
    #pragma unroll
    for (int i = ly; i < 32; i += 8) WT[(size_t)(mb + i) * K + kb + lx] = f2bf(t[lx][i] * scale);
}

// ---------- batched 256x256 transpose: 4 weights in ONE dispatch (z-indexed) ----------
__global__ __launch_bounds__(256)
void transpose_w4(const float* __restrict__ W0, const float* __restrict__ W1,
                  const float* __restrict__ W2, const float* __restrict__ W3,
                  u16* __restrict__ T0, u16* __restrict__ T1,
                  u16* __restrict__ T2, u16* __restrict__ T3, float s0)
{
    __shared__ float t[32][33];
    const int z = blockIdx.z;
    const float* W = (z == 0) ? W0 : (z == 1) ? W1 : (z == 2) ? W2 : W3;
    u16*       WT = (z == 0) ? T0 : (z == 1) ? T1 : (z == 2) ? T2 : T3;
    const float scale = (z == 0) ? s0 : 1.0f;
    const int mb = blockIdx.x * 32;
    const int kb = blockIdx.y * 32;
    const int lx = threadIdx.x & 31;
    const int ly = threadIdx.x >> 5;
    #pragma unroll
    for (int i = ly; i < 32; i += 8) t[i][lx] = W[(size_t)(kb + i) * DD + mb + lx];
    __syncthreads();
    #pragma unroll
    for (int i = ly; i < 32; i += 8) WT[(size_t)(mb + i) * DD + kb + lx] = f2bf(t[lx][i] * scale);
}

// ---------- pack 3 bias vectors (first one scaled) ----------
__global__ __launch_bounds__(256)
void pack_bias3(const float* __restrict__ a, const float* __restrict__ b,
                const float* __restrict__ c, float* __restrict__ out, float s0)
{
    const int i = threadIdx.x;
    out[i] = a[i] * s0; out[256 + i] = b[i]; out[512 + i] = c[i];
}

// ---------- fuse to-projection into space-QKV (proven r15-r18) ----------
__global__ __launch_bounds__(256)
void fuse_to_sqkv_w(const float* __restrict__ to_w,
                    const float* __restrict__ sq_w, const float* __restrict__ sk_w,
                    const float* __restrict__ sv_w, u16* __restrict__ wt_out)
{
    const int m = blockIdx.x;            // 0..767
    const int k = threadIdx.x;           // 0..255
    const float* Wsq = (m < 256) ? sq_w : (m < 512 ? sk_w : sv_w);
    const int mc = m & 255;
    float acc = 0.f;
    for (int j = 0; j < 256; j++)
        acc += to_w[k * 256 + j] * Wsq[j * 256 + mc];
    if (m < 256) acc *= S2F;
    wt_out[m * 256 + k] = f2bf(acc);
}
__global__ __launch_bounds__(256)
void fuse_to_sqkv_b(const float* __restrict__ to_b,
                    const float* __restrict__ sq_w, const float* __restrict__ sk_w,
                    const float* __restrict__ sv_w,
                    const float* __restrict__ sq_b, const float* __restrict__ sk_b,
                    const float* __restrict__ sv_b, float* __restrict__ b_out)
{
    const int m = blockIdx.x * 256 + threadIdx.x;
    const float* Wsq = (blockIdx.x == 0) ? sq_w : (blockIdx.x == 1 ? sk_w : sv_w);
    const float* bs  = (blockIdx.x == 0) ? sq_b : (blockIdx.x == 1 ? sk_b : sv_b);
    const int mc = m & 255;
    float acc = bs[mc];
    for (int j = 0; j < 256; j++) acc += to_b[j] * Wsq[j * 256 + mc];
    if (blockIdx.x == 0) acc *= S2F;
    b_out[m] = acc;
}

// ---------- f32 -> bf16 convert ----------
__global__ __launch_bounds__(256)
void cvt_bf16(const float* __restrict__ in, u16* __restrict__ out, int n8)
{
    for (int i = blockIdx.x * blockDim.x + threadIdx.x; i < n8; i += gridDim.x * blockDim.x) {
        float v[8];
        load8v(in + (size_t)i * 8, v);
        *(uint4*)(out + (size_t)i * 8) = pack8bf(v);
    }
}

// ---------- MFMA bf16 GEMM v6: 256x128 tile, BK=32, prefetch double-buffer ----------
// Short-K GEMMs (gqkv, fc1): 24KB LDS keeps multiple blocks/CU (R14/R16
// lessons: deep buffer only wins at high trip count; reg-staged A loses to
// global_load_lds because ds_write lands on the critical path).
__global__ __launch_bounds__(512)
void gemm_bt6(const u16* __restrict__ A, int lda,
              const u16* __restrict__ WT,
              const float* __restrict__ bias, u16* __restrict__ C,
              int K, int M, int relu)
{
    __shared__ u16 As0[256 * 32];
    __shared__ u16 As1[256 * 32];
    __shared__ u16 Bs0[128 * 32];
    __shared__ u16 Bs1[128 * 32];
    const int tid  = threadIdx.x;
    const int wid  = tid >> 6;          // 0..7
    const int lane = tid & 63;
    const int l16  = lane & 15;
    const int kg   = lane >> 4;

    const int nwg = gridDim.x * gridDim.y;
    int lin = blockIdx.y * gridDim.x + blockIdx.x;
    lin = (lin & 7) * (nwg >> 3) + (lin >> 3);
    const int row0 = (lin / gridDim.x) * 256;
    const int col0 = (lin % gridDim.x) * 128;

    const int srow = lane >> 2;
    const int gchunk = ((lane & 3) ^ ((srow >> 1) & 3)) * 8;  // inverse-swizzled source
    const int rchunk = (kg ^ ((l16 >> 1) & 3)) * 8;           // swizzled read

    const u16* Abase = A  + (size_t)(row0 + srow) * lda + gchunk;
    const u16* Bbase = WT + (size_t)(col0 + wid * 16 + srow) * K + gchunk;

    f32x4 acc[2][8];
    #pragma unroll
    for (int fr = 0; fr < 2; fr++)
        #pragma unroll
        for (int fc = 0; fc < 8; fc++)
            acc[fr][fc] = (f32x4){0.f, 0.f, 0.f, 0.f};

#define STAGE_T(ASB, BSB, k0)                                                   \
    do {                                                                        \
        _Pragma("unroll")                                                       \
        for (int q = 0; q < 2; q++) {                                           \
            const int rbase = wid * 32 + q * 16;                                \
            gl16(Abase + (size_t)rbase * lda + (k0), &ASB[rbase * 32]);         \
        }                                                                       \
        gl16(Bbase + (k0), &BSB[wid * 16 * 32]);                                \
    } while (0)

#define COMPUTE_T(ASB, BSB)                                                     \
    do {                                                                        \
        bf16x8 af[2], bfr[8];                                                   \
        _Pragma("unroll")                                                       \
        for (int fr = 0; fr < 2; fr++)                                          \
            af[fr] = *(const bf16x8*)(&ASB[(wid * 32 + fr * 16 + l16) * 32 + rchunk]); \
        _Pragma("unroll")                                                       \
        for (int fc = 0; fc < 8; fc++)                                          \
            bfr[fc] = *(const bf16x8*)(&BSB[(fc * 16 + l16) * 32 + rchunk]);    \
        _Pragma("unroll")                                                       \
        for (int fr = 0; fr < 2; fr++)                                          \
            _Pragma("unroll")                                                   \
            for (int fc = 0; fc < 8; fc++)                                      \
                acc[fr][fc] = __builtin_amdgcn_mfma_f32_16x16x32_bf16(af[fr], bfr[fc], acc[fr][fc], 0, 0, 0); \
    } while (0)

    STAGE_T(As0, Bs0, 0);
    __syncthreads();                       // implicit vmcnt(0): tile 0 ready

    for (int k0 = 0; k0 < K; k0 += 64) {
        if (k0 + 32 < K) STAGE_T(As1, Bs1, k0 + 32);
        COMPUTE_T(As0, Bs0);
        __syncthreads();
        if (k0 + 64 < K) STAGE_T(As0, Bs0, k0 + 64);
        COMPUTE_T(As1, Bs1);
        __syncthreads();
    }
#undef STAGE_T
#undef COMPUTE_T

    #pragma unroll
    for (int fr = 0; fr < 2; fr++) {
        #pragma unroll
        for (int fc = 0; fc < 8; fc++) {
            const int col = col0 + fc * 16 + l16;
            const float bv = bias[col];
            const int row = row0 + wid * 32 + fr * 16 + kg * 4;
            #pragma unroll
            for (int j = 0; j < 4; j += 2) {
                float x0 = acc[fr][fc][j]     + bv;
                float x1 = acc[fr][fc][j + 1] + bv;
                if (relu) { x0 = fmaxf(x0, 0.f); x1 = fmaxf(x1, 0.f); }
                const u32 pk = cvtpk2(x0, x1);
                C[(size_t)(row + j)     * M + col] = (u16)pk;
                C[(size_t)(row + j + 1) * M + col] = (u16)(pk >> 16);
            }
        }
    }
}

// ---------- MFMA bf16 GEMM v6h: 128x128 tile variant (fallback fc2) ----------
__global__ __launch_bounds__(512)
void gemm_bt6h(const u16* __restrict__ A, int lda,
               const u16* __restrict__ WT,
               const float* __restrict__ bias, u16* __restrict__ C,
               int K, int M, int relu)
{
    __shared__ u16 As0[128 * 32];
    __shared__ u16 As1[128 * 32];
    __shared__ u16 Bs0[128 * 32];
    __shared__ u16 Bs1[128 * 32];
    const int tid  = threadIdx.x;
    const int wid  = tid >> 6;          // 0..7
    const int lane = tid & 63;
    const int l16  = lane & 15;
    const int kg   = lane >> 4;

    const int nwg = gridDim.x * gridDim.y;
    int lin = blockIdx.y * gridDim.x + blockIdx.x;
    lin = (lin & 7) * (nwg >> 3) + (lin >> 3);
    const int row0 = (lin / gridDim.x) * 128;
    const int col0 = (lin % gridDim.x) * 128;

    const int srow = lane >> 2;
    const int gchunk = ((lane & 3) ^ ((srow >> 1) & 3)) * 8;
    const int rchunk = (kg ^ ((l16 >> 1) & 3)) * 8;

    const u16* Abase = A  + (size_t)(row0 + wid * 16 + srow) * lda + gchunk;
    const u16* Bbase = WT + (size_t)(col0 + wid * 16 + srow) * K + gchunk;

    f32x4 acc[8];
    #pragma unroll
    for (int fc = 0; fc < 8; fc++)
        acc[fc] = (f32x4){0.f, 0.f, 0.f, 0.f};

#define STAGE_H(ASB, BSB, k0)                                                   \
    do {                                                                        \
        gl16(Abase + (k0), &ASB[wid * 16 * 32]);                                \
        gl16(Bbase + (k0), &BSB[wid * 16 * 32]);                                \
    } while (0)

#define COMPUTE_H(ASB, BSB)                                                     \
    do {                                                                        \
        bf16x8 af, bfr[8];                                                      \
        af = *(const bf16x8*)(&ASB[(wid * 16 + l16) * 32 + rchunk]);            \
        _Pragma("unroll")                                                       \
        for (int fc = 0; fc < 8; fc++)                                          \
            bfr[fc] = *(const bf16x8*)(&BSB[(fc * 16 + l16) * 32 + rchunk]);    \
        _Pragma("unroll")                                                       \
        for (int fc = 0; fc < 8; fc++)                                          \
            acc[fc] = __builtin_amdgcn_mfma_f32_16x16x32_bf16(af, bfr[fc], acc[fc], 0, 0, 0); \
    } while (0)

    STAGE_H(As0, Bs0, 0);
    __syncthreads();

    for (int k0 = 0; k0 < K; k0 += 64) {
        if (k0 + 32 < K) STAGE_H(As1, Bs1, k0 + 32);
        COMPUTE_H(As0, Bs0);
        __syncthreads();
        if (k0 + 64 < K) STAGE_H(As0, Bs0, k0 + 64);
        COMPUTE_H(As1, Bs1);
        __syncthreads();
    }
#undef STAGE_H
#undef COMPUTE_H

    #pragma unroll
    for (int fc = 0; fc < 8; fc++) {
        const int col = col0 + fc * 16 + l16;
        const float bv = bias[col];
        const int row = row0 + wid * 16 + kg * 4;
        #pragma unroll
        for (int j = 0; j < 4; j += 2) {
            float x0 = acc[fc][j]     + bv;
            float x1 = acc[fc][j + 1] + bv;
            if (relu) { x0 = fmaxf(x0, 0.f); x1 = fmaxf(x1, 0.f); }
            const u32 pk = cvtpk2(x0, x1);
            C[(size_t)(row + j)     * M + col] = (u16)pk;
            C[(size_t)(row + j + 1) * M + col] = (u16)(pk >> 16);
        }
    }
}

// ---------- GEMM + residual + LN fused, 256x256, BK=64 dbuf (gd+ln1, fc2+ln2) ----------
// 18 ds_reads per 32 MFMA, grid NTOK/256 = 256 = 1 block/CU tail-free; BK=64
// deep dbuf halves barrier drains. Wins where LN fusion saves a full pass
// (both call sites) and, at K=1024, where trip count amortizes the drains.
template<typename TR, typename TO>
__global__ __launch_bounds__(512)
void gemm_ln2(const u16* __restrict__ A, int lda,
              const u16* __restrict__ WT,
              const float* __restrict__ bias,
              const TR* __restrict__ R,
              const float* __restrict__ gw, const float* __restrict__ bw,
              TO* __restrict__ out, int K)
{
    __shared__ u16 As0a[256 * 32];
    __shared__ u16 As0b[256 * 32];
    __shared__ u16 As1a[256 * 32];
    __shared__ u16 As1b[256 * 32];
    __shared__ u16 Bs0a[256 * 32];
    __shared__ u16 Bs0b[256 * 32];
    __shared__ u16 Bs1a[256 * 32];
    __shared__ u16 Bs1b[256 * 32];
    const int tid  = threadIdx.x;
    const int wid  = tid >> 6;          // 0..7
    const int lane = tid & 63;
    const int l16  = lane & 15;
    const int kg   = lane >> 4;

    const int nwg = gridDim.x;          // must be %8==0
    int lin = blockIdx.x;
    lin = (lin & 7) * (nwg >> 3) + (lin >> 3);
    const int row0 = lin * 256;

    const int srow = lane >> 2;
    const int gchunk = ((lane & 3) ^ ((srow >> 1) & 3)) * 8;
    const int rchunk = (kg ^ ((l16 >> 1) & 3)) * 8;

    const u16* Abase = A  + (size_t)(row0 + wid * 32 + srow) * lda + gchunk;
    const u16* Bbase = WT + (size_t)(wid * 32 + srow) * K + gchunk;

    f32x4 acc[2][16];
    #pragma unroll
    for (int fr = 0; fr < 2; fr++)
        #pragma unroll
        for (int fc = 0; fc < 16; fc++)
            acc[fr][fc] = (f32x4){0.f, 0.f, 0.f, 0.f};

#define STAGE_L2(ASA, ASB2, BSA, BSB2, k0)                                      \
    do {                                                                        \
        _Pragma("unroll")                                                       \
        for (int q = 0; q < 2; q++) {                                           \
            const int rbase = wid * 32 + q * 16;                                \
            gl16(Abase + (size_t)(q * 16) * lda + (k0),      &ASA[rbase * 32]); \
            gl16(Abase + (size_t)(q * 16) * lda + (k0) + 32, &ASB2[rbase * 32]);\
            gl16(Bbase + (size_t)(q * 16) * K   + (k0),      &BSA[rbase * 32]); \
            gl16(Bbase + (size_t)(q * 16) * K   + (k0) + 32, &BSB2[rbase * 32]);\
        }                                                                       \
    } while (0)

#define COMPUTE_L2(ASB, BSB)                                                    \
    do {                                                                        \
        bf16x8 af[2];                                                           \
        _Pragma("unroll")                                                       \
        for (int fr = 0; fr < 2; fr++)                                          \
            af[fr] = *(const bf16x8*)(&ASB[(wid * 32 + fr * 16 + l16) * 32 + rchunk]); \
        _Pragma("unroll")                                                       \
        for (int fc = 0; fc < 16; fc++) {                                       \
            bf16x8 bfr = *(const bf16x8*)(&BSB[(fc * 16 + l16) * 32 + rchunk]); \
            acc[0][fc] = __builtin_amdgcn_mfma_f32_16x16x32_bf16(af[0], bfr, acc[0][fc], 0, 0, 0); \
            acc[1][fc] = __builtin_amdgcn_mfma_f32_16x16x32_bf16(af[1], bfr, acc[1][fc], 0, 0, 0); \
        }                                                                       \
    } while (0)

    STAGE_L2(As0a, As0b, Bs0a, Bs0b, 0);
    __syncthreads();

    for (int k0 = 0; k0 < K; k0 += 128) {
        if (k0 + 64 < K) STAGE_L2(As1a, As1b, Bs1a, Bs1b, k0 + 64);
        COMPUTE_L2(As0a, Bs0a);
        COMPUTE_L2(As0b, Bs0b);
        __syncthreads();
        if (k0 + 128 < K) STAGE_L2(As0a, As0b, Bs0a, Bs0b, k0 + 128);
        COMPUTE_L2(As1a, Bs1a);
        COMPUTE_L2(As1b, Bs1b);
        __syncthreads();
    }
#undef STAGE_L2
#undef COMPUTE_L2

    float bia[16], gwv[16], bwv[16];
    #pragma unroll
    for (int fc = 0; fc < 16; fc++) {
        const int d = fc * 16 + l16;
        bia[fc] = bias[d]; gwv[fc] = gw[d]; bwv[fc] = bw[d];
    }
    #pragma unroll
    for (int fr = 0; fr < 2; fr++) {
        #pragma unroll
        for (int j = 0; j < 4; j++) {
            const int row = row0 + wid * 32 + fr * 16 + kg * 4 + j;
            const size_t rb = (size_t)row * DD + l16;
            float v[16];
            float s1 = 0.f, s2 = 0.f;
            #pragma unroll
            for (int fc = 0; fc < 16; fc++) {
                const float xv = acc[fr][fc][j] + bia[fc] + rload(R + rb + fc * 16);
                v[fc] = xv; s1 += xv; s2 += xv * xv;
            }
            #pragma unroll
            for (int o = 1; o < 16; o <<= 1) { s1 += __shfl_xor(s1, o); s2 += __shfl_xor(s2, o); }
            const float mean = s1 * (1.f / DD);
            const float var  = s2 * (1.f / DD) - mean * mean;
            const float rs   = rsqrtf(var + EPSV);
            #pragma unroll
            for (int fc = 0; fc < 16; fc++)
                sstore(out + rb + fc * 16, (v[fc] - mean) * rs * gwv[fc] + bwv[fc]);
        }
    }
}

// ---------- time attention v12: in-register P + MFMA row sums + pair cvt ----------
__global__ __launch_bounds__(256)
void time_attn12(const u16* __restrict__ F, int ld, u16* __restrict__ O)
{
    __shared__ u16 Ks2[2][64 * KP];
    __shared__ u16 Vt2[2][32 * VP6];
    const int bid = blockIdx.x;
    const int tid  = threadIdx.x;
    const int wid  = tid >> 6;
    const int lane = tid & 63;
    const int l16  = lane & 15;
    const int g    = lane >> 4;

    #pragma unroll
    for (int it = 0; it < 2; it++) {
        const int i = tid + it * 256;
        const int tu = i >> 8, rr = (i >> 2) & 63, p = i & 3;
        const int tau = bid * 2 + tu;
        const size_t ga = ((size_t)(tau >> 3) * 64 + rr) * ld + (tau & 7) * DKK + 256 + p * 8;
        *(uint4*)&Ks2[tu][rr * KP + p * 8] = *(const uint4*)(F + ga);
    }
    #pragma unroll
    for (int it = 0; it < 2; it++) {
        const int i = tid + it * 256;
        const int tu = i >> 8, p = (i >> 6) & 3, rr = i & 63;
        const int tau = bid * 2 + tu;
        const size_t ga = ((size_t)(tau >> 3) * 64 + rr) * ld + (tau & 7) * DKK + 512 + p * 8;
        uint4 vv = *(const uint4*)(F + ga);
        const u16* vp = (const u16*)&vv;
        #pragma unroll
        for (int j = 0; j < 8; j++) Vt2[tu][(p * 8 + j) * VP6 + rr] = vp[j];
    }
    __syncthreads();

    const int tu  = wid >> 1;
    const int tau = bid * 2 + tu;
    const int hc  = (tau & 7) * DKK;
    const size_t n0 = (size_t)(tau >> 3) * 64;
    const int q0  = (wid & 1) * 32;
    const f32x4 z4 = (f32x4){0.f, 0.f, 0.f, 0.f};
    const bf16x4 vone = (bf16x4){BF16_ONE, BF16_ONE, BF16_ONE, BF16_ONE};

    bf16x8 qf[2];
    #pragma unroll
    for (int f = 0; f < 2; f++)
        qf[f] = *(const bf16x8*)(F + (n0 + q0 + f * 16 + l16) * ld + hc + g * 8);

    f32x4 s[2][4];
    #pragma unroll
    for (int kt = 0; kt < 4; kt++) {
        bf16x8 kf = *(const bf16x8*)&Ks2[tu][(kt * 16 + l16) * KP + g * 8];
        s[0][kt] = __builtin_amdgcn_mfma_f32_16x16x32_bf16(kf, qf[0], z4, 0, 0, 0);
        s[1][kt] = __builtin_amdgcn_mfma_f32_16x16x32_bf16(kf, qf[1], z4, 0, 0, 0);
    }

    bf16x4 pp[2][4];
    #pragma unroll
    for (int f = 0; f < 2; f++) {
        #pragma unroll
        for (int kt = 0; kt < 4; kt++) {
            float pv[4];
            #pragma unroll
            for (int j = 0; j < 4; j++) pv[j] = EXP2(s[f][kt][j]);
            pp[f][kt] = packbf4(pv);
        }
    }

    f32x4 o[2][2];
    f32x4 lacc[2];
    #pragma unroll
    for (int f = 0; f < 2; f++) {
        lacc[f] = z4;
        #pragma unroll
        for (int hh = 0; hh < 2; hh++)
            o[f][hh] = z4;
    }
    #pragma unroll
    for (int kt = 0; kt < 4; kt++) {
        bf16x4 vf[2];
        #pragma unroll
        for (int hh = 0; hh < 2; hh++)
            vf[hh] = *(const bf16x4*)&Vt2[tu][(hh * 16 + l16) * VP6 + kt * 16 + g * 4];
        #pragma unroll
        for (int f = 0; f < 2; f++) {
            o[f][0] = mfma16(pp[f][kt], vf[0], o[f][0]);
            o[f][1] = mfma16(pp[f][kt], vf[1], o[f][1]);
            lacc[f] = mfma16(pp[f][kt], vone, lacc[f]);
        }
    }

    #pragma unroll
    for (int f = 0; f < 2; f++) {
        float iv[4];
        #pragma unroll
        for (int j = 0; j < 4; j++) iv[j] = 1.f / lacc[f][j];
        #pragma unroll
        for (int hh = 0; hh < 2; hh++) {
            const u32 p0 = cvtpk2(o[f][hh][0] * iv[0], o[f][hh][1] * iv[1]);
            const u32 p1 = cvtpk2(o[f][hh][2] * iv[2], o[f][hh][3] * iv[3]);
            const size_t ga0 = (n0 + q0 + f * 16 + g * 4) * DD + hc + hh * 16 + l16;  // AO: ld=DD
            O[ga0]          = (u16)p0;
            O[ga0 + DD]     = (u16)(p0 >> 16);
            O[ga0 + 2 * DD] = (u16)p1;
            O[ga0 + 3 * DD] = (u16)(p1 >> 16);
        }
    }
}

// ---------- space attention v16: async dbuf + MFMA row sums + pair cvt + setprio ----------
__global__ __launch_bounds__(512, 4)
void space_attn16(u16* __restrict__ F, int ld)
{
    __shared__ u16 Ks[2][128 * KPS];
    __shared__ u16 Vt[2][32 * VH];
    const int bid = blockIdx.x;             // (b*H + h)*T + t
    const int t  = bid & (TT_ - 1);
    const int h  = (bid >> 6) & (HH - 1);
    const int b  = bid >> 9;
    const int hc = h * DKK;
    const int tid  = threadIdx.x;
    const int wid  = tid >> 6;
    const int lane = tid & 63;
    const int l16  = lane & 15;
    const int g    = lane >> 4;

    const int kr = tid >> 2, kp = tid & 3;
    const int vr = tid & 127, vp = tid >> 7;
    const size_t rowstr = (size_t)TT_ * ld;
    const size_t base0  = ((size_t)(b * SS) * TT_ + t) * ld + hc;

    const int q0 = wid * 64;
    bf16x8 qf[4];
    #pragma unroll
    for (int f = 0; f < 4; f++) {
        const int s = q0 + f * 16 + l16;
        qf[f] = *(const bf16x8*)(F + base0 + (size_t)s * rowstr + g * 8);
    }

    uint4 kreg = *(const uint4*)(F + base0 + 256 + (size_t)kr * rowstr + kp * 8);
    uint4 vreg = *(const uint4*)(F + base0 + 512 + (size_t)vr * rowstr + vp * 8);
    *(uint4*)&Ks[0][kr * KPS + kp * 8] = kreg;
    {
        const u16* vpp = (const u16*)&vreg;
        #pragma unroll
        for (int j = 0; j < 8; j++) Vt[0][(vp * 8 + j) * VH + vr] = vpp[j];
    }
    __syncthreads();

    f32x4 o[4][2];
    f32x4 lacc[4];
    const f32x4 z4 = (f32x4){0.f, 0.f, 0.f, 0.f};
    const bf16x4 vone = (bf16x4){BF16_ONE, BF16_ONE, BF16_ONE, BF16_ONE};
    #pragma unroll
    for (int f = 0; f < 4; f++) {
        lacc[f] = z4;
        #pragma unroll
        for (int hh = 0; hh < 2; hh++)
            o[f][hh] = z4;
    }

    for (int qtr = 0; qtr < 4; qtr++) {
        const int cur = qtr & 1;
        if (qtr < 3) {
            const int key = (qtr + 1) * 128;
            kreg = *(const uint4*)(F + base0 + 256 + (size_t)(key + kr) * rowstr + kp * 8);
            vreg = *(const uint4*)(F + base0 + 512 + (size_t)(key + vr) * rowstr + vp * 8);
        }

        for (int kc2 = 0; kc2 < 4; kc2++) {
            bf16x8 kfa = *(const bf16x8*)&Ks[cur][(kc2 * 32 +      l16) * KPS + g * 8];
            bf16x8 kfb = *(const bf16x8*)&Ks[cur][(kc2 * 32 + 16 + l16) * KPS + g * 8];

            bf16x4 pa[4], pb[4];
            #pragma unroll
            for (int f = 0; f < 4; f++) {
                f32x4 sa = __builtin_amdgcn_mfma_f32_16x16x32_bf16(kfa, qf[f], z4, 0, 0, 0);
                f32x4 sb = __builtin_amdgcn_mfma_f32_16x16x32_bf16(kfb, qf[f], z4, 0, 0, 0);
                float pva[4], pvb[4];
                #pragma unroll
                for (int j = 0; j < 4; j++) pva[j] = EXP2(sa[j]);
                #pragma unroll
                for (int j = 0; j < 4; j++) pvb[j] = EXP2(sb[j]);
                pa[f] = packbf4(pva);
                pb[f] = packbf4(pvb);
            }

            bf16x4 va[2][2];
            #pragma unroll
            for (int hh = 0; hh < 2; hh++)
                #pragma unroll
                for (int u = 0; u < 2; u++)
                    va[hh][u] = *(const bf16x4*)&Vt[cur][(hh * 16 + l16) * VH + kc2 * 32 + u * 16 + g * 4];

            __builtin_amdgcn_s_setprio(1);
            #pragma unroll
            for (int f = 0; f < 4; f++) {
                #pragma unroll
                for (int hh = 0; hh < 2; hh++) {
                    o[f][hh] = mfma16(pa[f], va[hh][0], o[f][hh]);
                    o[f][hh] = mfma16(pb[f], va[hh][1], o[f][hh]);
                }
                lacc[f] = mfma16(pa[f], vone, lacc[f]);
                lacc[f] = mfma16(pb[f], vone, lacc[f]);
            }
            __builtin_amdgcn_s_setprio(0);
        }

        if (qtr < 3) {
            __syncthreads();
            *(uint4*)&Ks[cur ^ 1][kr * KPS + kp * 8] = kreg;
            const u16* vpp = (const u16*)&vreg;
            #pragma unroll
            for (int j = 0; j < 8; j++) Vt[cur ^ 1][(vp * 8 + j) * VH + vr] = vpp[j];
            __syncthreads();
        }
    }

    #pragma unroll
    for (int f = 0; f < 4; f++) {
        float iv[4];
        #pragma unroll
        for (int j = 0; j < 4; j++) iv[j] = 1.f / lacc[f][j];
        const int s = q0 + f * 16 + g * 4;
        #pragma unroll
        for (int hh = 0; hh < 2; hh++) {
            const u32 p0 = cvtpk2(o[f][hh][0] * iv[0], o[f][hh][1] * iv[1]);
            const u32 p1 = cvtpk2(o[f][hh][2] * iv[2], o[f][hh][3] * iv[3]);
            const size_t ga0 = base0 + (size_t)s * rowstr + hh * 16 + l16;
            F[ga0]              = (u16)p0;
            F[ga0 + rowstr]     = (u16)(p0 >> 16);
            F[ga0 + 2 * rowstr] = (u16)p1;
            F[ga0 + 3 * rowstr] = (u16)(p1 >> 16);
        }
    }
}

// ---------- residual add + LayerNorm (fallback path) ----------
template<typename T1, typename TO>
__global__ __launch_bounds__(256)
void add_ln(const T1* __restrict__ X1, const u16* __restrict__ X2,
            const float* __restrict__ gw, const float* __restrict__ bw,
            TO* __restrict__ out)
{
    const int row  = blockIdx.x * 4 + (threadIdx.x >> 6);
    const int lane = threadIdx.x & 63;
    const size_t base = (size_t)row * DD + lane * 4;
    float v[4], w2[4];
    load4v(X1 + base, v);
    load4v(X2 + base, w2);
    v[0] += w2[0]; v[1] += w2[1]; v[2] += w2[2]; v[3] += w2[3];
    float s1 = v[0] + v[1] + v[2] + v[3];
    float s2 = v[0]*v[0] + v[1]*v[1] + v[2]*v[2] + v[3]*v[3];
    #pragma unroll
    for (int o = 1; o < 64; o <<= 1) { s1 += __shfl_xor(s1, o); s2 += __shfl_xor(s2, o); }
    const float mean = s1 * (1.f / DD);
    const float var  = s2 * (1.f / DD) - mean * mean;
    const float rs   = rsqrtf(var + EPSV);
    float o4[4];
    #pragma unroll
    for (int i = 0; i < 4; i++) {
        const int d = lane * 4 + i;
        o4[i] = (v[i] - mean) * rs * gw[d] + bw[d];
    }
    store4o(out + base, o4);
}

// ---------- launch ----------
extern "C" void kernel_launch(void* const* d_in, const int* in_sizes, int n_in,
                              void* d_out, int out_size, void* d_ws, size_t ws_size,
                              hipStream_t stream)
{
    (void)in_sizes; (void)n_in; (void)out_size;
    const float* x     = (const float*)d_in[0];
    const float* tq_w  = (const float*)d_in[1];
    const float* tq_b  = (const float*)d_in[2];
    const float* tk_w  = (const float*)d_in[3];
    const float* tk_b  = (const float*)d_in[4];
    const float* tv_w  = (const float*)d_in[5];
    const float* tv_b  = (const float*)d_in[6];
    const float* to_w  = (const float*)d_in[7];
    const float* to_b  = (const float*)d_in[8];
    const float* sq_w  = (const float*)d_in[9];
    const float* sq_b  = (const float*)d_in[10];
    const float* sk_w  = (const float*)d_in[11];
    const float* sk_b  = (const float*)d_in[12];
    const float* sv_w  = (const float*)d_in[13];
    const float* sv_b  = (const float*)d_in[14];
    const float* so_w  = (const float*)d_in[15];
    const float* so_b  = (const float*)d_in[16];
    const float* fc1_w = (const float*)d_in[17];
    const float* fc1_b = (const float*)d_in[18];
    const float* fc2_w = (const float*)d_in[19];
    const float* fc2_b = (const float*)d_in[20];
    const float* ln1_w = (const float*)d_in[21];
    const float* ln1_b = (const float*)d_in[22];
    const float* ln2_w = (const float*)d_in[23];
    const float* ln2_b = (const float*)d_in[24];

    const size_t SLOT = (size_t)NTOK * DD;   // elems (33.5 MB as u16)
    u16*   F  = (u16*)d_ws;                  // fused [N][768] activations = slots 0-2
    u16*   OA = (u16*)d_out;                 // bf16 scratch: xbf -> AO (dead after gqkv2)
    float* HD = (float*)d_out;               // f32 final output

    // ffn1 layout (ws >= 6 slots): F 0-2 | W1FF 0-3 (F dead) | WTb slot 4 | HB slot 5
    const bool ffn1 = ws_size >= 6 * SLOT * sizeof(u16);
    u16*   WTb = ffn1 ? ((u16*)d_ws + 4 * SLOT)
                      : (u16*)((char*)d_out + (61u << 20));
    float* BIb = ffn1 ? (float*)((u16*)d_ws + 4 * SLOT + 983040)
                      : (float*)((char*)d_out + (63u << 20));

    u16* wt_tqkv  = WTb;                     // [768][256]
    u16* wt_fused = wt_tqkv + 3 * 65536;     // fused to*sqkv [768][256]
    u16* wt_so    = wt_fused + 3 * 65536;
    u16* wt_fc1   = wt_so + 65536;
    u16* wt_fc2   = wt_fc1 + 262144;         // ends at elem 983040 (1.92MB)
    float* b_tqkv  = BIb;                    // 768
    float* b_fused = BIb + 768;              // 768

    dim3 blk(256);
    dim3 blk5(512);

    // 4 square transposes in ONE dispatch (z-indexed); fc1/fc2 separate shapes
    transpose_w4<<<dim3(DD / 32, DD / 32, 4), blk, 0, stream>>>(
        tq_w, tk_w, tv_w, so_w,
        wt_tqkv, wt_tqkv + 65536, wt_tqkv + 2 * 65536, wt_so, S2F);
    transpose_w<<<dim3(FFF / 32, DD / 32), blk, 0, stream>>>(fc1_w, wt_fc1, DD, FFF, 1.0f);
    transpose_w<<<dim3(DD / 32, FFF / 32), blk, 0, stream>>>(fc2_w, wt_fc2, FFF, DD, 1.0f);
    pack_bias3<<<1, blk, 0, stream>>>(tq_b, tk_b, tv_b, b_tqkv, S2F);
    fuse_to_sqkv_w<<<768, blk, 0, stream>>>(to_w, sq_w, sk_w, sv_w, wt_fused);
    fuse_to_sqkv_b<<<3, blk, 0, stream>>>(to_b, sq_w, sk_w, sv_w, sq_b, sk_b, sv_b, b_fused);

    // bf16(x) -> OA (d_out scratch; no aliasing with F)
    cvt_bf16<<<2048, blk, 0, stream>>>(x, OA, (int)(SLOT / 8));

    // 256-row tiles: grids (cols, rows/256); all nwg % 8 == 0 for XCD swizzle
    dim3 gqkv(768 / 128, NTOK / 256);        // (6, 256) = 1536

    // ---- time attention: QKV -> F; attn out (AO) -> OA ----
    gemm_bt6<<<gqkv, blk5, 0, stream>>>(OA, DD, wt_tqkv, b_tqkv, F, DD, 768, 0);
    time_attn12<<<BB * HH * SS / 2, blk, 0, stream>>>(F, 768, OA);

    // ---- space attention: fused (to*sqkv) projection AO -> F; attn in-place ----
    gemm_bt6<<<gqkv, blk5, 0, stream>>>(OA, DD, wt_fused, b_fused, F, DD, 768, 0);
    space_attn16<<<BB * HH * TT_, blk5, 0, stream>>>(F, 768);

    if (ffn1) {
        u16* HB   = (u16*)d_ws + 5 * SLOT;   // h = LN1(x + so), slot 5
        u16* W1FF = (u16*)d_ws;              // FFN intermediate, slots 0-3 (F dead after gd_ln)
        // gd + ln1 fused (256x256 BK=64, K=256): reads F (slots 0-2) + x -> HB (slot 5)
        gemm_ln2<float, u16><<<NTOK / 256, blk5, 0, stream>>>(
            F, 768, wt_so, so_b, x, ln1_w, ln1_b, HB, DD);
        // fc1 (256x128 BK=32, multi-block/CU): reads HB (slot 5), writes W1FF (slots 0-3)
        gemm_bt6<<<dim3(FFF / 128, NTOK / 256), blk5, 0, stream>>>(
            HB, DD, wt_fc1, fc1_b, W1FF, DD, FFF, 1);
        // fc2 + ln2 fused (256x256 BK=64, K=1024): W1FF (0-3) + HB (5) + wt (4) -> HD
        gemm_ln2<u16, float><<<NTOK / 256, blk5, 0, stream>>>(
            W1FF, FFF, wt_fc2, fc2_b, HB, ln2_w, ln2_b, HD, FFF);
    } else {
        // ---- fallback: R9 path (weights in d_out; add_ln separate dispatches) ----
        u16* W0 = (u16*)d_ws;
        u16* W1 = W0 + SLOT;
        u16* W2 = W1 + SLOT;
        dim3 gd(DD / 128, NTOK / 256);
        gemm_bt6<<<gd, blk5, 0, stream>>>(F, 768, wt_so, so_b, OA, DD, DD, 0);
        add_ln<float, u16><<<NTOK / 4, blk, 0, stream>>>(x, OA, ln1_w, ln1_b, W0);
        for (int c = 0; c < 4; c++) {
            const size_t off = (size_t)c * 16384 * DD;
            gemm_bt6<<<dim3(FFF / 128, 16384 / 256), blk5, 0, stream>>>(W0 + off, DD, wt_fc1, fc1_b, W1, DD, FFF, 1);
            gemm_bt6h<<<dim3(DD / 128, 16384 / 128), blk5, 0, stream>>>(W1, FFF, wt_fc2, fc2_b, W2, FFF, DD, 0);
            add_ln<u16, float><<<16384 / 4, blk, 0, stream>>>(W0 + off, W2, ln2_w, ln2_b, HD + off);
        }
    }
}